// Round 1
// baseline (855.591 us; speedup 1.0000x reference)
//
#include <hip/hip_runtime.h>
#include <math.h>

#define TPB 256

constexpr int Bn = 8, Cn = 3, Hn = 1024, Wn = 512;
constexpr long long HWn  = (long long)Hn * Wn;      // 524288 = 2^19
constexpr long long CHWn = (long long)Cn * HWn;     // 1572864
constexpr float INV_NTOT = 1.0f / (float)(Cn * Hn * Wn);
constexpr float EPS10 = 4.5399929762484854e-05f;    // exp(-10)

// ---------------------------------------------------------------------------
// Forward FFT along W (512) — one block per row, real input -> complex out
// ---------------------------------------------------------------------------
__global__ __launch_bounds__(TPB) void k_fft_w_fwd(const float* __restrict__ x,
                                                   float2* __restrict__ F) {
    __shared__ float sre[Wn], sim[Wn], twc[Wn / 2], tws[Wn / 2];
    int r = blockIdx.x;                     // B*C*H rows
    const float* xr = x + (long long)r * Wn;
    float2* Fr = F + (long long)r * Wn;
    int t = threadIdx.x;

    if (t < Wn / 2) {
        float s, c;
        sincospif(-2.0f * (float)t / (float)Wn, &s, &c);  // e^{-2pi i t/512}
        twc[t] = c; tws[t] = s;
    }
    for (int i = t; i < Wn; i += TPB) {
        int j = __brev((unsigned)i) >> (32 - 9);
        sre[j] = xr[i];
        sim[j] = 0.0f;
    }
    __syncthreads();
    #pragma unroll
    for (int st = 0; st < 9; st++) {
        int half = 1 << st;
        int i = t;                           // exactly 256 butterflies
        int blk = i >> st, j = i & (half - 1);
        int pos = (blk << (st + 1)) + j;
        int tid = j << (8 - st);
        float c = twc[tid], s = tws[tid];
        float ure = sre[pos], uim = sim[pos];
        float vre = sre[pos + half], vim = sim[pos + half];
        float tre = vre * c - vim * s, tim = vre * s + vim * c;
        sre[pos] = ure + tre;  sim[pos] = uim + tim;
        sre[pos + half] = ure - tre;  sim[pos + half] = uim - tim;
        __syncthreads();
    }
    for (int i = t; i < Wn; i += TPB)
        Fr[i] = make_float2(sre[i], sim[i]);
}

// ---------------------------------------------------------------------------
// Inverse FFT along W (512) fused with |z| * 1/Ntot -> real SRabs
// ---------------------------------------------------------------------------
__global__ __launch_bounds__(TPB) void k_ifft_w_abs(const float2* __restrict__ F,
                                                    float* __restrict__ SRabs) {
    __shared__ float sre[Wn], sim[Wn], twc[Wn / 2], tws[Wn / 2];
    int r = blockIdx.x;
    const float2* Fr = F + (long long)r * Wn;
    float* outr = SRabs + (long long)r * Wn;
    int t = threadIdx.x;

    if (t < Wn / 2) {
        float s, c;
        sincospif(2.0f * (float)t / (float)Wn, &s, &c);   // conjugate twiddles
        twc[t] = c; tws[t] = s;
    }
    for (int i = t; i < Wn; i += TPB) {
        int j = __brev((unsigned)i) >> (32 - 9);
        float2 z = Fr[i];
        sre[j] = z.x;
        sim[j] = z.y;
    }
    __syncthreads();
    #pragma unroll
    for (int st = 0; st < 9; st++) {
        int half = 1 << st;
        int i = t;
        int blk = i >> st, j = i & (half - 1);
        int pos = (blk << (st + 1)) + j;
        int tid = j << (8 - st);
        float c = twc[tid], s = tws[tid];
        float ure = sre[pos], uim = sim[pos];
        float vre = sre[pos + half], vim = sim[pos + half];
        float tre = vre * c - vim * s, tim = vre * s + vim * c;
        sre[pos] = ure + tre;  sim[pos] = uim + tim;
        sre[pos + half] = ure - tre;  sim[pos + half] = uim - tim;
        __syncthreads();
    }
    for (int i = t; i < Wn; i += TPB) {
        float re = sre[i], im = sim[i];
        outr[i] = sqrtf(re * re + im * im) * INV_NTOT;
    }
}

// ---------------------------------------------------------------------------
// FFT along H (1024), strided by W complexes. TW=4 w-columns per block.
// INV=0 forward, INV=1 inverse (no scaling here).
// ---------------------------------------------------------------------------
template <int INV>
__global__ __launch_bounds__(TPB) void k_fft_h(float2* __restrict__ F) {
    __shared__ float sre[4][Hn], sim[4][Hn], twc[Hn / 2], tws[Hn / 2];
    int bid = blockIdx.x;
    int wt = bid & 127;            // W/4 = 128 tiles
    int bc = bid >> 7;             // b*C + c
    float2* base = F + (long long)bc * HWn + wt * 4;
    int t = threadIdx.x;

    for (int i = t; i < Hn / 2; i += TPB) {
        float s, c;
        sincospif((INV ? 2.0f : -2.0f) * (float)i / (float)Hn, &s, &c);
        twc[i] = c; tws[i] = s;
    }
    for (int i = t; i < 4 * Hn; i += TPB) {
        int w = i & 3, h = i >> 2;
        float2 z = base[(long long)h * Wn + w];
        int hj = __brev((unsigned)h) >> (32 - 10);
        sre[w][hj] = z.x;
        sim[w][hj] = z.y;
    }
    __syncthreads();
    #pragma unroll
    for (int st = 0; st < 10; st++) {
        int half = 1 << st;
        #pragma unroll
        for (int qq = 0; qq < 8; qq++) {           // 2048 butterflies / 256 thr
            int q = qq * TPB + t;
            int w = q >> 9;
            int i = q & 511;
            int blk = i >> st, j = i & (half - 1);
            int pos = (blk << (st + 1)) + j;
            int tid = j << (9 - st);
            float c = twc[tid], s = tws[tid];
            float ure = sre[w][pos], uim = sim[w][pos];
            float vre = sre[w][pos + half], vim = sim[w][pos + half];
            float tre = vre * c - vim * s, tim = vre * s + vim * c;
            sre[w][pos] = ure + tre;  sim[w][pos] = uim + tim;
            sre[w][pos + half] = ure - tre;  sim[w][pos + half] = uim - tim;
        }
        __syncthreads();
    }
    for (int i = t; i < 4 * Hn; i += TPB) {
        int w = i & 3, h = i >> 2;
        base[(long long)h * Wn + w] = make_float2(sre[w][h], sim[w][h]);
    }
}

// ---------------------------------------------------------------------------
// 3-point DFT along C (stride HW), forward, fused with log-amplitude
// ---------------------------------------------------------------------------
__global__ __launch_bounds__(TPB) void k_dft_c_fwd(float2* __restrict__ F,
                                                   float* __restrict__ LA) {
    long long idx = (long long)blockIdx.x * TPB + threadIdx.x;   // over B*HW
    if (idx >= (long long)Bn * HWn) return;
    long long b = idx >> 19;
    long long p = idx & (HWn - 1);
    float2* z = F + b * CHWn + p;
    float2 z0 = z[0], z1 = z[HWn], z2 = z[2 * HWn];
    const float s3 = 0.86602540378443864676f;
    float sx = z1.x + z2.x, sy = z1.y + z2.y;
    float dx = z1.x - z2.x, dy = z1.y - z2.y;
    float2 X0 = make_float2(z0.x + sx, z0.y + sy);
    float2 X1 = make_float2(z0.x - 0.5f * sx + s3 * dy, z0.y - 0.5f * sy - s3 * dx);
    float2 X2 = make_float2(z0.x - 0.5f * sx - s3 * dy, z0.y - 0.5f * sy + s3 * dx);
    z[0] = X0; z[HWn] = X1; z[2 * HWn] = X2;
    float* la = LA + b * CHWn + p;
    la[0]        = logf(sqrtf(X0.x * X0.x + X0.y * X0.y) + EPS10);
    la[HWn]      = logf(sqrtf(X1.x * X1.x + X1.y * X1.y) + EPS10);
    la[2 * HWn]  = logf(sqrtf(X2.x * X2.x + X2.y * X2.y) + EPS10);
}

// Inverse 3-point DFT along C (conjugate twiddles == swap X1/X2 formulas)
__global__ __launch_bounds__(TPB) void k_dft_c_inv(float2* __restrict__ F) {
    long long idx = (long long)blockIdx.x * TPB + threadIdx.x;
    if (idx >= (long long)Bn * HWn) return;
    long long b = idx >> 19;
    long long p = idx & (HWn - 1);
    float2* z = F + b * CHWn + p;
    float2 z0 = z[0], z1 = z[HWn], z2 = z[2 * HWn];
    const float s3 = 0.86602540378443864676f;
    float sx = z1.x + z2.x, sy = z1.y + z2.y;
    float dx = z1.x - z2.x, dy = z1.y - z2.y;
    float2 X0 = make_float2(z0.x + sx, z0.y + sy);
    float2 X1 = make_float2(z0.x - 0.5f * sx - s3 * dy, z0.y - 0.5f * sy + s3 * dx);
    float2 X2 = make_float2(z0.x - 0.5f * sx + s3 * dy, z0.y - 0.5f * sy - s3 * dx);
    z[0] = X0; z[HWn] = X1; z[2 * HWn] = X2;
}

// ---------------------------------------------------------------------------
// 3x3 channel-summed box conv (zero pad): AF[b,h,w] = 1/9 * sum_c sum_3x3 LA
// ---------------------------------------------------------------------------
__global__ __launch_bounds__(TPB) void k_avgconv(const float* __restrict__ LA,
                                                 float* __restrict__ AF) {
    __shared__ float tile[3][10][34];
    int w0 = blockIdx.x << 5;
    int h0 = blockIdx.y << 3;
    int b = blockIdx.z;
    int t = threadIdx.x;
    for (int i = t; i < 3 * 10 * 34; i += TPB) {
        int c = i / 340, rem = i - c * 340;
        int hh = rem / 34, ww = rem - hh * 34;
        int h = h0 + hh - 1, w = w0 + ww - 1;
        float v = 0.0f;
        if ((unsigned)h < (unsigned)Hn && (unsigned)w < (unsigned)Wn)
            v = LA[((long long)b * 3 + c) * HWn + (long long)h * Wn + w];
        tile[c][hh][ww] = v;
    }
    __syncthreads();
    int ww = t & 31, hh = t >> 5;
    float acc = 0.0f;
    #pragma unroll
    for (int c = 0; c < 3; c++)
        #pragma unroll
        for (int dh = 0; dh < 3; dh++)
            #pragma unroll
            for (int dw = 0; dw < 3; dw++)
                acc += tile[c][hh + dh][ww + dw];
    AF[(long long)b * HWn + (long long)(h0 + hh) * Wn + (w0 + ww)] = acc * (1.0f / 9.0f);
}

// ---------------------------------------------------------------------------
// G = exp(LA - AF) * F/|F|   (phase preserved; |F|==0 -> (exp,0))
// ---------------------------------------------------------------------------
__global__ __launch_bounds__(TPB) void k_compose(float2* __restrict__ F,
                                                 const float* __restrict__ LA,
                                                 const float* __restrict__ AF) {
    long long idx = (long long)blockIdx.x * TPB + threadIdx.x;   // over B*C*HW
    if (idx >= (long long)Bn * CHWn) return;
    long long b = idx / CHWn;
    long long q = idx & (HWn - 1);
    float2 z = F[idx];
    float la = LA[idx];
    float af = AF[b * HWn + q];
    float m = expf(la - af);
    float r = sqrtf(z.x * z.x + z.y * z.y);
    float2 g;
    if (r > 0.0f) {
        float sc = m / r;
        g = make_float2(z.x * sc, z.y * sc);
    } else {
        g = make_float2(m, 0.0f);
    }
    F[idx] = g;
}

// ---------------------------------------------------------------------------
// 3x3 channel-summed Gaussian conv (zero pad) -> SRg (B,H,W)
// ---------------------------------------------------------------------------
__global__ __launch_bounds__(TPB) void k_gauconv(const float* __restrict__ SRa,
                                                 float* __restrict__ SRg) {
    __shared__ float tile[3][10][34];
    int w0 = blockIdx.x << 5;
    int h0 = blockIdx.y << 3;
    int b = blockIdx.z;
    int t = threadIdx.x;
    for (int i = t; i < 3 * 10 * 34; i += TPB) {
        int c = i / 340, rem = i - c * 340;
        int hh = rem / 34, ww = rem - hh * 34;
        int h = h0 + hh - 1, w = w0 + ww - 1;
        float v = 0.0f;
        if ((unsigned)h < (unsigned)Hn && (unsigned)w < (unsigned)Wn)
            v = SRa[((long long)b * 3 + c) * HWn + (long long)h * Wn + w];
        tile[c][hh][ww] = v;
    }
    __syncthreads();
    const float g16 = 1.0f / 16.0f, g8 = 1.0f / 8.0f, g4 = 1.0f / 4.0f;
    const float wgt[3][3] = {{g16, g8, g16}, {g8, g4, g8}, {g16, g8, g16}};
    int ww = t & 31, hh = t >> 5;
    float acc = 0.0f;
    #pragma unroll
    for (int c = 0; c < 3; c++)
        #pragma unroll
        for (int dh = 0; dh < 3; dh++)
            #pragma unroll
            for (int dw = 0; dw < 3; dw++)
                acc += wgt[dh][dw] * tile[c][hh + dh][ww + dw];
    SRg[(long long)b * HWn + (long long)(h0 + hh) * Wn + (w0 + ww)] = acc;
}

// ---------------------------------------------------------------------------
// Per-batch mean of SRg -> mean[8] (mean buffer must be zeroed)
// ---------------------------------------------------------------------------
__global__ __launch_bounds__(TPB) void k_mean(const float* __restrict__ SRg,
                                              float* __restrict__ mean) {
    int b = blockIdx.y;
    long long base = (long long)b * HWn + (long long)blockIdx.x * 2048;
    float s = 0.0f;
    #pragma unroll
    for (int k2 = 0; k2 < 8; k2++)
        s += SRg[base + k2 * TPB + threadIdx.x];
    #pragma unroll
    for (int o = 32; o > 0; o >>= 1)
        s += __shfl_down(s, o);
    __shared__ float ls[4];
    int lane = threadIdx.x & 63, wv = threadIdx.x >> 6;
    if (lane == 0) ls[wv] = s;
    __syncthreads();
    if (threadIdx.x == 0) {
        float tot = ls[0] + ls[1] + ls[2] + ls[3];
        atomicAdd(&mean[b], tot * (1.0f / (float)HWn));
    }
}

// ---------------------------------------------------------------------------
// Final: out[b,h,o] = b_out[o] + sum_{w,k} thr(SRg[b,(h+k-1)%H,w]) * w_out[o,w,k]
// 64h x 64o tile per block, 4x4 per thread, fp32 vector FMA.
// ---------------------------------------------------------------------------
__global__ __launch_bounds__(TPB) void k_outgemm(const float* __restrict__ SRg,
                                                 const float* __restrict__ mean,
                                                 const float* __restrict__ w_out,
                                                 const float* __restrict__ b_out,
                                                 float* __restrict__ out) {
    __shared__ __align__(16) float As[66][33];
    __shared__ __align__(16) float Bs[3][32][64];
    int o0 = blockIdx.x << 6;
    int h0 = blockIdx.y << 6;
    int b = blockIdx.z;
    int t = threadIdx.x;
    int to = t & 15, th = t >> 4;
    float meanb = mean[b];
    const float* srb = SRg + (long long)b * HWn;

    float acc[4][4];
    #pragma unroll
    for (int i = 0; i < 4; i++)
        #pragma unroll
        for (int j = 0; j < 4; j++) acc[i][j] = 0.0f;

    for (int w0 = 0; w0 < Wn; w0 += 32) {
        // A tile: rows h0-1 .. h0+64 (wrap), 32 w columns; threshold applied
        for (int i = t; i < 66 * 32; i += TPB) {
            int r = i >> 5, wc = i & 31;
            int h = (h0 - 1 + r) & (Hn - 1);
            float v = srb[(long long)h * Wn + w0 + wc];
            As[r][wc] = (v > meanb) ? v : 0.0f;
        }
        // B tile: w_out[o][w][k] -> Bs[k][w][oo]
        {
            int oo = t & 63, g = t >> 6;
            const float4* wpv = (const float4*)(w_out +
                (long long)(o0 + oo) * 1536 + (long long)w0 * 3 + g * 24);
            #pragma unroll
            for (int j2 = 0; j2 < 6; j2++) {
                float4 v4 = wpv[j2];
                int mm = j2 * 4;
                Bs[(mm) % 3][g * 8 + (mm) / 3][oo]         = v4.x;
                Bs[(mm + 1) % 3][g * 8 + (mm + 1) / 3][oo] = v4.y;
                Bs[(mm + 2) % 3][g * 8 + (mm + 2) / 3][oo] = v4.z;
                Bs[(mm + 3) % 3][g * 8 + (mm + 3) / 3][oo] = v4.w;
            }
        }
        __syncthreads();
        for (int w = 0; w < 32; w++) {
            float a6[6];
            #pragma unroll
            for (int j = 0; j < 6; j++) a6[j] = As[(th << 2) + j][w];
            #pragma unroll
            for (int k = 0; k < 3; k++) {
                float4 bv = *(const float4*)&Bs[k][w][to << 2];
                #pragma unroll
                for (int i2 = 0; i2 < 4; i2++) {
                    acc[i2][0] += a6[i2 + k] * bv.x;
                    acc[i2][1] += a6[i2 + k] * bv.y;
                    acc[i2][2] += a6[i2 + k] * bv.z;
                    acc[i2][3] += a6[i2 + k] * bv.w;
                }
            }
        }
        __syncthreads();
    }

    float4 bias = *(const float4*)&b_out[o0 + (to << 2)];
    #pragma unroll
    for (int i2 = 0; i2 < 4; i2++) {
        int h = h0 + (th << 2) + i2;
        float4 v = make_float4(acc[i2][0] + bias.x, acc[i2][1] + bias.y,
                               acc[i2][2] + bias.z, acc[i2][3] + bias.w);
        *(float4*)&out[((long long)b * Hn + h) * 512 + o0 + (to << 2)] = v;
    }
}

// ---------------------------------------------------------------------------
extern "C" void kernel_launch(void* const* d_in, const int* in_sizes, int n_in,
                              void* d_out, int out_size, void* d_ws, size_t ws_size,
                              hipStream_t stream) {
    (void)in_sizes; (void)n_in; (void)out_size;
    const float* x     = (const float*)d_in[0];
    const float* w_out = (const float*)d_in[1];
    const float* b_out = (const float*)d_in[2];
    float* out = (float*)d_out;

    const size_t CBUF_BYTES = (size_t)Bn * CHWn * sizeof(float2);  // 100663296
    const size_t LA_BYTES   = (size_t)Bn * CHWn * sizeof(float);   //  50331648
    const size_t AF_BYTES   = (size_t)Bn * HWn * sizeof(float);    //  16777216
    const size_t NEED = CBUF_BYTES + LA_BYTES + AF_BYTES + 32;
    if (ws_size < NEED) return;  // workspace too small -> validation will flag

    char* ws = (char*)d_ws;
    float2* CBUF = (float2*)ws;
    float*  LA   = (float*)(ws + CBUF_BYTES);
    float*  AF   = (float*)(ws + CBUF_BYTES + LA_BYTES);
    float*  MEAN = (float*)(ws + CBUF_BYTES + LA_BYTES + AF_BYTES);

    hipMemsetAsync(MEAN, 0, 8 * sizeof(float), stream);

    // forward FFT: W, H, C (C fused with log-amp)
    k_fft_w_fwd<<<Bn * Cn * Hn, TPB, 0, stream>>>(x, CBUF);
    k_fft_h<0><<<Bn * Cn * (Wn / 4), TPB, 0, stream>>>(CBUF);
    k_dft_c_fwd<<<(int)((Bn * HWn) / TPB), TPB, 0, stream>>>(CBUF, LA);

    // spectral residual
    k_avgconv<<<dim3(Wn / 32, Hn / 8, Bn), TPB, 0, stream>>>(LA, AF);
    k_compose<<<(int)((Bn * CHWn) / TPB), TPB, 0, stream>>>(CBUF, LA, AF);

    // inverse FFT: C, H, W (W fused with abs + 1/N)
    k_dft_c_inv<<<(int)((Bn * HWn) / TPB), TPB, 0, stream>>>(CBUF);
    k_fft_h<1><<<Bn * Cn * (Wn / 4), TPB, 0, stream>>>(CBUF);
    k_ifft_w_abs<<<Bn * Cn * Hn, TPB, 0, stream>>>(CBUF, LA);   // SRabs -> LA

    // gaussian conv + mean + threshold(in GEMM) + output conv
    k_gauconv<<<dim3(Wn / 32, Hn / 8, Bn), TPB, 0, stream>>>(LA, AF);  // SRg -> AF
    k_mean<<<dim3(256, Bn), TPB, 0, stream>>>(AF, MEAN);
    k_outgemm<<<dim3(8, 16, Bn), TPB, 0, stream>>>(AF, MEAN, w_out, b_out, out);
}